// Round 1
// baseline (351.777 us; speedup 1.0000x reference)
//
#include <hip/hip_runtime.h>

namespace {
constexpr int NC    = 20;
constexpr int NA    = 5;
constexpr int GH    = 19;
constexpr int GW    = 19;
constexpr int NCELL = GH * GW;        // 361
constexpr int NBOX  = NA * NCELL;     // 1805
constexpr int SORTN = 2048;
constexpr int NT    = 1024;           // threads per block
constexpr int TMAX  = 50;
constexpr float CONF_T = 0.5f;
constexpr float NMS_T  = 0.45f;
constexpr float IOU_T  = 0.5f;
}

__device__ __constant__ float d_anchw[NA] = {1.3221f, 3.19275f, 5.05587f, 9.47112f, 11.2364f};
__device__ __constant__ float d_anchh[NA] = {1.73145f, 4.00944f, 8.09892f, 4.84053f, 10.0071f};

// One block per batch image. Phases: decode -> bitonic sort (stable, desc conf)
// -> greedy NMS over valid prefix -> GT matching -> atomics into counters.
__global__ __launch_bounds__(NT, 1) void yolo_main(
    const float* __restrict__ net,    // [B, 125, 19, 19]
    const float* __restrict__ tgt,    // [B, 250]
    float4* __restrict__ rawbox,      // ws: [B, NBOX] cx,cy,w,h
    int* __restrict__ counters)       // ws: [proposals, correct, total]
{
    __shared__ unsigned long long skey[SORTN];
    __shared__ float sx1[NBOX], sy1[NBOX], sx2[NBOX], sy2[NBOX];
    __shared__ float sw[NBOX], sh[NBOX];
    __shared__ unsigned char keep[NBOX];
    __shared__ int sM, sNV, sProp, sCorr;

    const int b   = blockIdx.x;
    const int tid = threadIdx.x;
    const float* op = net + (size_t)b * (NA * (5 + NC) * NCELL);
    float4* rb = rawbox + (size_t)b * NBOX;

    if (tid == 0) {
        sM = 0; sProp = 0; sCorr = 0;
        // num_gts: count rows until first cx == 0 (cumprod semantics)
        int v = 0;
        while (v < TMAX && tgt[b * 250 + v * 5 + 1] != 0.0f) v++;
        sNV = v;
    }

    // ---- decode ----
    for (int n = tid; n < NBOX; n += NT) {
        int a = n / NCELL;
        int r = n - a * NCELL;
        int y = r / GW;
        int x = r - y * GW;
        int base = a * 25 * NCELL + r;     // channel stride = 361
        float t0 = op[base];
        float t1 = op[base + 1 * NCELL];
        float t2 = op[base + 2 * NCELL];
        float t3 = op[base + 3 * NCELL];
        float t4 = op[base + 4 * NCELL];
        float cx = (1.0f / (1.0f + expf(-t0)) + (float)x) / 19.0f;
        float cy = (1.0f / (1.0f + expf(-t1)) + (float)y) / 19.0f;
        float bw = expf(t2) * (d_anchw[a] / 19.0f);
        float bh = expf(t3) * (d_anchh[a] / 19.0f);
        float det = 1.0f / (1.0f + expf(-t4));
        rb[n] = make_float4(cx, cy, bw, bh);
        // ascending sort key == stable argsort(-det): hi=~det_bits, lo=idx
        skey[n] = ((unsigned long long)(~__float_as_uint(det)) << 32) | (unsigned)n;
    }
    for (int n = NBOX + tid; n < SORTN; n += NT) skey[n] = ~0ull;  // pad sinks last

    // ---- bitonic sort (ascending), 2048 elems, 1024 threads ----
    for (unsigned k = 2; k <= SORTN; k <<= 1) {
        for (unsigned j = k >> 1; j > 0; j >>= 1) {
            __syncthreads();
            unsigned i = ((tid & ~(j - 1)) << 1) | (tid & (j - 1));
            unsigned p = i | j;
            unsigned long long va = skey[i], vb = skey[p];
            bool up = ((i & k) == 0);
            if ((va > vb) == up) { skey[i] = vb; skey[p] = va; }
        }
    }
    __syncthreads();

    // ---- gather into sorted corner form; find M = |{det > 0.5}| (prefix) ----
    for (int p = tid; p < NBOX; p += NT) {
        unsigned long long kk = skey[p];
        int n = (int)(unsigned)kk;
        float det = __uint_as_float(~(unsigned)(kk >> 32));
        float4 bx = rb[n];                  // __syncthreads ordered the global writes
        sx1[p] = bx.x - 0.5f * bx.z;
        sx2[p] = bx.x + 0.5f * bx.z;
        sy1[p] = bx.y - 0.5f * bx.w;
        sy2[p] = bx.y + 0.5f * bx.w;
        sw[p]  = bx.z;
        sh[p]  = bx.w;
        bool v = det > CONF_T;
        keep[p] = v ? 1 : 0;
        if (v) {
            float dn = 0.0f;
            if (p + 1 < NBOX) dn = __uint_as_float(~(unsigned)(skey[p + 1] >> 32));
            if (!(dn > CONF_T)) sM = p + 1;  // unique boundary thread
        }
    }
    __syncthreads();
    const int M = sM;

    // ---- greedy NMS: serial over i, parallel over j. Sync only on kept i. ----
    for (int i = 0; i < M - 1; ++i) {
        if (keep[i]) {                       // block-uniform read
            float ax1 = sx1[i], ax2 = sx2[i], ay1 = sy1[i], ay2 = sy2[i];
            float aw = sw[i], ah = sh[i], aarea = aw * ah;
            for (int j = i + 1 + tid; j < M; j += NT) {
                if (keep[j]) {
                    float uw = fmaxf(ax2, sx2[j]) - fminf(ax1, sx1[j]);
                    float uh = fmaxf(ay2, sy2[j]) - fminf(ay1, sy1[j]);
                    float cw = aw + sw[j] - uw;
                    float ch = ah + sh[j] - uh;
                    if (cw > 0.0f && ch > 0.0f) {
                        float ca = cw * ch;
                        float ua = aarea + sw[j] * sh[j] - ca;
                        if (ca > NMS_T * ua) keep[j] = 0;   // iou > thresh
                    }
                }
            }
            __syncthreads();
        }
    }

    // ---- proposals = popcount(keep[0..M)) ----
    int cnt = 0;
    for (int p = tid; p < M; p += NT) cnt += keep[p];
    for (int d = 32; d > 0; d >>= 1) cnt += __shfl_down(cnt, d, 64);
    if ((tid & 63) == 0) atomicAdd(&sProp, cnt);

    // ---- GT matching: one wave per GT row, lanes stripe kept boxes ----
    const int nv   = sNV;
    const int wid  = tid >> 6;
    const int lane = tid & 63;
    for (int t = wid; t < nv; t += (NT / 64)) {
        const float* g = tgt + b * 250 + t * 5;
        float gcx = g[1], gcy = g[2], gw = g[3], gh = g[4];
        float gx1 = gcx - 0.5f * gw, gx2 = gcx + 0.5f * gw;
        float gy1 = gcy - 0.5f * gh, gy2 = gcy + 0.5f * gh;
        float garea = gw * gh;
        float best = 0.0f;
        for (int j = lane; j < M; j += 64) {
            if (!keep[j]) continue;
            float uw = fmaxf(gx2, sx2[j]) - fminf(gx1, sx1[j]);
            float uh = fmaxf(gy2, sy2[j]) - fminf(gy1, sy1[j]);
            float cw = gw + sw[j] - uw;
            float ch = gh + sh[j] - uh;
            float ca = (cw > 0.0f && ch > 0.0f) ? cw * ch : 0.0f;
            float ua = garea + sw[j] * sh[j] - ca;
            best = fmaxf(best, ca / ua);
        }
        for (int d = 32; d > 0; d >>= 1) best = fmaxf(best, __shfl_down(best, d, 64));
        if (lane == 0 && best > IOU_T) atomicAdd(&sCorr, 1);
    }
    __syncthreads();

    if (tid == 0) {
        atomicAdd(counters + 0, sProp);
        atomicAdd(counters + 1, sCorr);
        atomicAdd(counters + 2, nv);
    }
}

__global__ void yolo_final(const int* __restrict__ counters, float* __restrict__ out) {
    if (threadIdx.x == 0 && blockIdx.x == 0) {
        float prop  = (float)counters[0];
        float corr  = (float)counters[1];
        float total = (float)counters[2];
        float prec = corr / (prop + 1e-6f);
        float rec  = corr / (total + 1e-6f);
        float fs   = 2.0f * prec * rec / (prec + rec + 1e-6f);
        out[0] = total;
        out[1] = prop;
        out[2] = corr;
        out[3] = prec;
        out[4] = rec;
        out[5] = fs;
    }
}

extern "C" void kernel_launch(void* const* d_in, const int* in_sizes, int n_in,
                              void* d_out, int out_size, void* d_ws, size_t ws_size,
                              hipStream_t stream) {
    const float* net = (const float*)d_in[0];   // [8,125,19,19] f32
    const float* tgt = (const float*)d_in[1];   // [8,250] f32
    int*    counters = (int*)d_ws;                               // 3 ints
    float4* rawbox   = (float4*)((char*)d_ws + 256);             // 8*1805*16 B

    hipMemsetAsync(counters, 0, 3 * sizeof(int), stream);
    yolo_main<<<8, NT, 0, stream>>>(net, tgt, rawbox, counters);
    yolo_final<<<1, 64, 0, stream>>>(counters, (float*)d_out);
}

// Round 2
// 209.259 us; speedup vs baseline: 1.6811x; 1.6811x over previous
//
#include <hip/hip_runtime.h>

namespace {
constexpr int NA    = 5;
constexpr int NCELL = 361;            // 19*19
constexpr int NBOX  = 1805;           // NA * NCELL
constexpr int SORTN = 2048;
constexpr int NT1   = 1024;
constexpr int TMAX  = 50;
constexpr float CONF_T = 0.5f;
constexpr float NMS_T  = 0.45f;
constexpr float IOU_T  = 0.5f;

constexpr int SOA_STRIDE = 1824;                  // padded per-batch stride (floats)
constexpr int SOA_ARR    = 8 * SOA_STRIDE;        // elems per array
constexpr int SUP_ROWS   = 1816;                  // rows/batch allocated (8 pad rows for prefetch overrun)
constexpr int SUP_WORDS  = 32;                    // u64 words per row
// ws offsets (bytes)
constexpr size_t WS_COUNT = 0;       // 4 ints
constexpr size_t WS_M     = 64;      // 8 ints
constexpr size_t WS_SOA   = 256;     // 6 arrays * SOA_ARR floats = 350,208 B
constexpr size_t WS_SUP   = 458752;  // 8 * 1816 * 32 * 8 = 3,719,168 B
}

__device__ __constant__ float d_anchw[NA] = {1.3221f, 3.19275f, 5.05587f, 9.47112f, 11.2364f};
__device__ __constant__ float d_anchh[NA] = {1.73145f, 4.00944f, 8.09892f, 4.84053f, 10.0071f};

__device__ inline unsigned long long shflw(unsigned long long v, int src) {
    int lo = __shfl((int)(unsigned)(v & 0xffffffffull), src, 64);
    int hi = __shfl((int)(unsigned)(v >> 32), src, 64);
    return ((unsigned long long)(unsigned)hi << 32) | (unsigned)lo;
}

// ---- K1: decode + stable conf-desc bitonic sort + SoA corner-form write ----
__global__ __launch_bounds__(NT1, 1) void k_decode_sort(
    const float* __restrict__ net, float* __restrict__ soa, int* __restrict__ Marr)
{
    __shared__ unsigned long long skey[SORTN];
    __shared__ float4 sbox[NBOX];
    __shared__ int sM;
    const int b = blockIdx.x, tid = threadIdx.x;
    const float* op = net + (size_t)b * (NA * 25 * NCELL);
    if (tid == 0) sM = 0;

    for (int n = tid; n < NBOX; n += NT1) {
        int a = n / NCELL;
        int r = n - a * NCELL;
        int y = r / 19;
        int x = r - y * 19;
        int base = a * 25 * NCELL + r;
        float t0 = op[base];
        float t1 = op[base + 1 * NCELL];
        float t2 = op[base + 2 * NCELL];
        float t3 = op[base + 3 * NCELL];
        float t4 = op[base + 4 * NCELL];
        float cx = (1.0f / (1.0f + expf(-t0)) + (float)x) / 19.0f;
        float cy = (1.0f / (1.0f + expf(-t1)) + (float)y) / 19.0f;
        float bw = expf(t2) * (d_anchw[a] / 19.0f);
        float bh = expf(t3) * (d_anchh[a] / 19.0f);
        float det = 1.0f / (1.0f + expf(-t4));
        sbox[n] = make_float4(cx, cy, bw, bh);
        skey[n] = ((unsigned long long)(~__float_as_uint(det)) << 32) | (unsigned)n;
    }
    for (int n = NBOX + tid; n < SORTN; n += NT1) skey[n] = ~0ull;

    for (unsigned k = 2; k <= SORTN; k <<= 1) {
        for (unsigned j = k >> 1; j > 0; j >>= 1) {
            __syncthreads();
            unsigned i = ((tid & ~(j - 1)) << 1) | (tid & (j - 1));
            unsigned p = i | j;
            unsigned long long va = skey[i], vb = skey[p];
            bool up = ((i & k) == 0);
            if ((va > vb) == up) { skey[i] = vb; skey[p] = va; }
        }
    }
    __syncthreads();

    float* X1 = soa + 0 * SOA_ARR + b * SOA_STRIDE;
    float* Y1 = soa + 1 * SOA_ARR + b * SOA_STRIDE;
    float* X2 = soa + 2 * SOA_ARR + b * SOA_STRIDE;
    float* Y2 = soa + 3 * SOA_ARR + b * SOA_STRIDE;
    float* Wd = soa + 4 * SOA_ARR + b * SOA_STRIDE;
    float* Hd = soa + 5 * SOA_ARR + b * SOA_STRIDE;
    for (int p = tid; p < NBOX; p += NT1) {
        unsigned long long kk = skey[p];
        int n = (int)(unsigned)(kk & 0xffffffffull);
        float det = __uint_as_float(~(unsigned)(kk >> 32));
        float4 bx = sbox[n];
        X1[p] = bx.x - 0.5f * bx.z;
        Y1[p] = bx.y - 0.5f * bx.w;
        X2[p] = bx.x + 0.5f * bx.z;
        Y2[p] = bx.y + 0.5f * bx.w;
        Wd[p] = bx.z;
        Hd[p] = bx.w;
        if (det > CONF_T) {
            float dn = 0.0f;
            if (p + 1 < NBOX) dn = __uint_as_float(~(unsigned)(skey[p + 1] >> 32));
            if (!(dn > CONF_T)) sM = p + 1;      // unique boundary thread
        }
    }
    __syncthreads();
    if (tid == 0) Marr[b] = sM;
}

// ---- K2: parallel suppression bitmask. One wave per sorted row i. ----
__global__ __launch_bounds__(256) void k_iou_mask(
    const float* __restrict__ soa, const int* __restrict__ Marr,
    unsigned long long* __restrict__ sup)
{
    const int b = blockIdx.y;
    const int lane = threadIdx.x & 63;
    const int i = blockIdx.x * 4 + (threadIdx.x >> 6);
    const int M = Marr[b];
    if (i >= M) return;
    const float* X1 = soa + 0 * SOA_ARR + b * SOA_STRIDE;
    const float* Y1 = soa + 1 * SOA_ARR + b * SOA_STRIDE;
    const float* X2 = soa + 2 * SOA_ARR + b * SOA_STRIDE;
    const float* Y2 = soa + 3 * SOA_ARR + b * SOA_STRIDE;
    const float* Wd = soa + 4 * SOA_ARR + b * SOA_STRIDE;
    const float* Hd = soa + 5 * SOA_ARR + b * SOA_STRIDE;
    float ax1 = X1[i], ay1 = Y1[i], ax2 = X2[i], ay2 = Y2[i];
    float aw = Wd[i], ah = Hd[i], aarea = aw * ah;
    const int nch = (M + 63) >> 6;
    unsigned long long myw = 0;
    for (int w = 0; w < nch; ++w) {
        int j = (w << 6) + lane;
        bool pred = false;
        if (j > i && j < M) {
            float bw = Wd[j], bh = Hd[j];
            float uw = fmaxf(ax2, X2[j]) - fminf(ax1, X1[j]);
            float uh = fmaxf(ay2, Y2[j]) - fminf(ay1, Y1[j]);
            float cw = aw + bw - uw;
            float ch = ah + bh - uh;
            if (cw > 0.0f && ch > 0.0f) {
                float ca = cw * ch;
                float ua = aarea + bw * bh - ca;
                pred = ca > NMS_T * ua;          // iou > thresh
            }
        }
        unsigned long long m = __ballot(pred);
        if (w == lane) myw = m;
    }
    unsigned long long* row = sup + ((size_t)b * SUP_ROWS + i) * SUP_WORDS;
    if (lane < SUP_WORDS) row[lane] = (lane < nch) ? myw : 0ull;
}

// ---- K3: serial greedy bit-sweep (wave 0) + proposal count + GT matching ----
__global__ __launch_bounds__(256) void k_nms_match(
    const float* __restrict__ soa, const float* __restrict__ tgt,
    const int* __restrict__ Marr, const unsigned long long* __restrict__ sup,
    int* __restrict__ counters)
{
    __shared__ unsigned long long kw[SUP_WORDS];
    __shared__ int sProp, sCorr, sNV;
    const int b = blockIdx.x, tid = threadIdx.x;
    const int wv = tid >> 6, lane = tid & 63;
    const int M = Marr[b];
    const int nch = (M + 63) >> 6;

    if (wv == 0) {
        // GT count via ballot (first row with cx==0)
        float cxv = (lane < TMAX) ? tgt[b * 250 + lane * 5 + 1] : 0.0f;
        unsigned long long bm = __ballot(cxv != 0.0f);
        unsigned long long inv = (~bm) & ((1ull << TMAX) - 1);
        int nv = inv ? (__ffsll(inv) - 1) : TMAX;
        if (lane == 0) { sNV = nv; sCorr = 0; }

        // greedy scan: lane l owns word min(l,31); all lanes track current word rmw
        const unsigned long long* sp = sup + (size_t)b * SUP_ROWS * SUP_WORDS;
        const int mylw = (lane < SUP_WORDS) ? lane : (SUP_WORDS - 1);
        unsigned long long rm = 0, rmw = 0;
        unsigned long long qo0, qo1, qo2, qo3, qb0, qb1, qb2, qb3;
        qo0 = sp[0 * SUP_WORDS + mylw]; qb0 = sp[0 * SUP_WORDS + 0];
        qo1 = sp[1 * SUP_WORDS + mylw]; qb1 = sp[1 * SUP_WORDS + 0];
        qo2 = sp[2 * SUP_WORDS + mylw]; qb2 = sp[2 * SUP_WORDS + 0];
        qo3 = sp[3 * SUP_WORDS + mylw]; qb3 = sp[3 * SUP_WORDS + 0];

        for (int i0 = 0; i0 < M; i0 += 4) {
            const unsigned long long* np_ = sp + (size_t)(i0 + 4) * SUP_WORDS;
            int w4 = (i0 + 4) >> 6, w5 = (i0 + 5) >> 6, w6 = (i0 + 6) >> 6, w7 = (i0 + 7) >> 6;
            {
                int i = i0;
                bool kept = (i < M) && !((rmw >> (i & 63)) & 1);
                unsigned long long o = qo0, q = qb0;
                qo0 = np_[0 * SUP_WORDS + mylw]; qb0 = np_[0 * SUP_WORDS + w4];
                if (kept) { rm |= o; rmw |= q; }
            }
            {
                int i = i0 + 1;
                bool kept = (i < M) && !((rmw >> (i & 63)) & 1);
                unsigned long long o = qo1, q = qb1;
                qo1 = np_[1 * SUP_WORDS + mylw]; qb1 = np_[1 * SUP_WORDS + w5];
                if (kept) { rm |= o; rmw |= q; }
            }
            {
                int i = i0 + 2;
                bool kept = (i < M) && !((rmw >> (i & 63)) & 1);
                unsigned long long o = qo2, q = qb2;
                qo2 = np_[2 * SUP_WORDS + mylw]; qb2 = np_[2 * SUP_WORDS + w6];
                if (kept) { rm |= o; rmw |= q; }
            }
            {
                int i = i0 + 3;
                bool kept = (i < M) && !((rmw >> (i & 63)) & 1);
                unsigned long long o = qo3, q = qb3;
                qo3 = np_[3 * SUP_WORDS + mylw]; qb3 = np_[3 * SUP_WORDS + w7];
                if (kept) { rm |= o; rmw |= q; }
                // word boundary: refresh rmw from owner lane of next word
                if (((i0 + 4) & 63) == 0) {
                    int nw2 = (i0 + 4) >> 6;
                    rmw = shflw(rm, (nw2 < SUP_WORDS) ? nw2 : (SUP_WORDS - 1));
                }
            }
        }

        unsigned long long keepv = 0;
        if (lane < nch) {
            int rem = M - (lane << 6);
            unsigned long long vm = (rem >= 64) ? ~0ull : ((1ull << rem) - 1ull);
            keepv = (~rm) & vm;
        }
        if (lane < SUP_WORDS) kw[lane] = keepv;
        int pc = __popcll(keepv);
        for (int d = 32; d > 0; d >>= 1) pc += __shfl_down(pc, d, 64);
        if (lane == 0) sProp = pc;
    }
    __syncthreads();

    // GT matching: wave per GT row
    const float* X1 = soa + 0 * SOA_ARR + b * SOA_STRIDE;
    const float* Y1 = soa + 1 * SOA_ARR + b * SOA_STRIDE;
    const float* X2 = soa + 2 * SOA_ARR + b * SOA_STRIDE;
    const float* Y2 = soa + 3 * SOA_ARR + b * SOA_STRIDE;
    const float* Wd = soa + 4 * SOA_ARR + b * SOA_STRIDE;
    const float* Hd = soa + 5 * SOA_ARR + b * SOA_STRIDE;
    const int nv = sNV;
    for (int t = wv; t < nv; t += 4) {
        const float* g = tgt + b * 250 + t * 5;
        float gcx = g[1], gcy = g[2], gw = g[3], gh = g[4];
        float gx1 = gcx - 0.5f * gw, gx2 = gcx + 0.5f * gw;
        float gy1 = gcy - 0.5f * gh, gy2 = gcy + 0.5f * gh;
        float garea = gw * gh;
        float best = 0.0f;
        for (int j = lane; j < M; j += 64) {
            if (!((kw[j >> 6] >> (j & 63)) & 1)) continue;
            float bw = Wd[j], bh = Hd[j];
            float uw = fmaxf(gx2, X2[j]) - fminf(gx1, X1[j]);
            float uh = fmaxf(gy2, Y2[j]) - fminf(gy1, Y1[j]);
            float cw = gw + bw - uw;
            float ch = gh + bh - uh;
            float ca = (cw > 0.0f && ch > 0.0f) ? cw * ch : 0.0f;
            float ua = garea + bw * bh - ca;
            best = fmaxf(best, ca / ua);
        }
        for (int d = 32; d > 0; d >>= 1) best = fmaxf(best, __shfl_down(best, d, 64));
        if (lane == 0 && best > IOU_T) atomicAdd(&sCorr, 1);
    }
    __syncthreads();
    if (tid == 0) {
        atomicAdd(counters + 0, sProp);
        atomicAdd(counters + 1, sCorr);
        atomicAdd(counters + 2, sNV);
    }
}

__global__ void yolo_final(const int* __restrict__ counters, float* __restrict__ out) {
    if (threadIdx.x == 0 && blockIdx.x == 0) {
        float prop  = (float)counters[0];
        float corr  = (float)counters[1];
        float total = (float)counters[2];
        float prec = corr / (prop + 1e-6f);
        float rec  = corr / (total + 1e-6f);
        float fs   = 2.0f * prec * rec / (prec + rec + 1e-6f);
        out[0] = total;
        out[1] = prop;
        out[2] = corr;
        out[3] = prec;
        out[4] = rec;
        out[5] = fs;
    }
}

extern "C" void kernel_launch(void* const* d_in, const int* in_sizes, int n_in,
                              void* d_out, int out_size, void* d_ws, size_t ws_size,
                              hipStream_t stream) {
    const float* net = (const float*)d_in[0];   // [8,125,19,19] f32
    const float* tgt = (const float*)d_in[1];   // [8,250] f32
    char* ws = (char*)d_ws;
    int* counters = (int*)(ws + WS_COUNT);
    int* Marr     = (int*)(ws + WS_M);
    float* soa    = (float*)(ws + WS_SOA);
    unsigned long long* sup = (unsigned long long*)(ws + WS_SUP);

    hipMemsetAsync(counters, 0, 16, stream);
    k_decode_sort<<<8, NT1, 0, stream>>>(net, soa, Marr);
    dim3 g2((NBOX + 3) / 4, 8);
    k_iou_mask<<<g2, 256, 0, stream>>>(soa, Marr, sup);
    k_nms_match<<<8, 256, 0, stream>>>(soa, tgt, Marr, sup, counters);
    yolo_final<<<1, 64, 0, stream>>>(counters, (float*)d_out);
}

// Round 3
// 205.222 us; speedup vs baseline: 1.7141x; 1.0197x over previous
//
#include <hip/hip_runtime.h>

namespace {
constexpr int NA    = 5;
constexpr int NCELL = 361;            // 19*19
constexpr int NBOX  = 1805;           // NA * NCELL
constexpr int SORTN = 2048;
constexpr int NT1   = 256;            // K1 threads (8 elems/thread register bitonic)
constexpr int TMAX  = 50;
constexpr float CONF_T = 0.5f;
constexpr float NMS_T  = 0.45f;
constexpr float IOU_T  = 0.5f;

constexpr int SOA_STRIDE = 1824;                  // padded per-batch stride (floats)
constexpr int SOA_ARR    = 8 * SOA_STRIDE;        // elems per array
constexpr int SUP_ROWS   = 1816;                  // rows/batch allocated
constexpr int SUP_WORDS  = 32;                    // u64 words per row
// ws offsets (bytes) — same footprint as R2 (known-good)
constexpr size_t WS_COUNT = 0;       // 4 ints: prop, corr, total, done
constexpr size_t WS_M     = 64;      // 8 ints
constexpr size_t WS_SOA   = 256;     // 6 * SOA_ARR floats
constexpr size_t WS_SUP   = 458752;  // 8 * 1816 * 32 * 8 B
}

__device__ __constant__ float d_anchw[NA] = {1.3221f, 3.19275f, 5.05587f, 9.47112f, 11.2364f};
__device__ __constant__ float d_anchh[NA] = {1.73145f, 4.00944f, 8.09892f, 4.84053f, 10.0071f};

__device__ inline unsigned long long shflw(unsigned long long v, int src) {
    int lo = __shfl((int)(unsigned)(v & 0xffffffffull), src, 64);
    int hi = __shfl((int)(unsigned)(v >> 32), src, 64);
    return ((unsigned long long)(unsigned)hi << 32) | (unsigned)lo;
}

// ---- K1: decode + register-blocked bitonic sort (256 thr x 8 elems) + SoA ----
__global__ __launch_bounds__(NT1, 1) void k_decode_sort(
    const float* __restrict__ net, float* __restrict__ soa, int* __restrict__ Marr)
{
    __shared__ unsigned long long skey[SORTN];   // 16 KB
    __shared__ float4 sbox[NBOX];                // 28.9 KB
    __shared__ int sM;
    const int b = blockIdx.x, tid = threadIdx.x;
    const float* op = net + (size_t)b * (NA * 25 * NCELL);
    if (tid == 0) sM = 0;

    for (int n = tid; n < NBOX; n += NT1) {
        int a = n / NCELL;
        int r = n - a * NCELL;
        int y = r / 19;
        int x = r - y * 19;
        int base = a * 25 * NCELL + r;
        float t0 = op[base];
        float t1 = op[base + 1 * NCELL];
        float t2 = op[base + 2 * NCELL];
        float t3 = op[base + 3 * NCELL];
        float t4 = op[base + 4 * NCELL];
        float cx = (1.0f / (1.0f + expf(-t0)) + (float)x) / 19.0f;
        float cy = (1.0f / (1.0f + expf(-t1)) + (float)y) / 19.0f;
        float bw = expf(t2) * (d_anchw[a] / 19.0f);
        float bh = expf(t3) * (d_anchh[a] / 19.0f);
        float det = 1.0f / (1.0f + expf(-t4));
        sbox[n] = make_float4(cx, cy, bw, bh);
        skey[n] = ((unsigned long long)(~__float_as_uint(det)) << 32) | (unsigned)n;
    }
    for (int n = NBOX + tid; n < SORTN; n += NT1) skey[n] = ~0ull;
    __syncthreads();

    unsigned long long v[8];
    const int base8 = tid << 3;
    auto cas = [&](int x, int y, bool up) {
        unsigned long long a = v[x], c = v[y];
        if ((a > c) == up) { v[x] = c; v[y] = a; }
    };

    // phases k=2,4,8 fully in registers
    {
        #pragma unroll
        for (int p = 0; p < 8; ++p) v[p] = skey[base8 + p];
        // k=2, j=1
        cas(0,1,true); cas(2,3,false); cas(4,5,true); cas(6,7,false);
        // k=4, j=2
        cas(0,2,true); cas(1,3,true); cas(4,6,false); cas(5,7,false);
        // k=4, j=1
        cas(0,1,true); cas(2,3,true); cas(4,5,false); cas(6,7,false);
        // k=8
        bool u8 = ((base8 & 8) == 0);
        cas(0,4,u8); cas(1,5,u8); cas(2,6,u8); cas(3,7,u8);
        cas(0,2,u8); cas(1,3,u8); cas(4,6,u8); cas(5,7,u8);
        cas(0,1,u8); cas(2,3,u8); cas(4,5,u8); cas(6,7,u8);
        #pragma unroll
        for (int p = 0; p < 8; ++p) skey[base8 + p] = v[p];
    }
    __syncthreads();

    for (unsigned k = 16; k <= SORTN; k <<= 1) {
        // cross-thread steps j >= 8 via LDS
        for (unsigned j = k >> 1; j >= 8; j >>= 1) {
            #pragma unroll
            for (int c = 0; c < 4; ++c) {
                unsigned m = (tid << 2) + c;
                unsigned i = ((m & ~(j - 1)) << 1) | (m & (j - 1));
                unsigned p = i | j;
                bool up = ((i & k) == 0);
                unsigned long long a = skey[i], c2 = skey[p];
                if ((a > c2) == up) { skey[i] = c2; skey[p] = a; }
            }
            __syncthreads();
        }
        // local tail j=4,2,1 (direction uniform per 8-chunk)
        {
            #pragma unroll
            for (int p = 0; p < 8; ++p) v[p] = skey[base8 + p];
            bool up = ((base8 & k) == 0);
            cas(0,4,up); cas(1,5,up); cas(2,6,up); cas(3,7,up);
            cas(0,2,up); cas(1,3,up); cas(4,6,up); cas(5,7,up);
            cas(0,1,up); cas(2,3,up); cas(4,5,up); cas(6,7,up);
            #pragma unroll
            for (int p = 0; p < 8; ++p) skey[base8 + p] = v[p];
        }
        __syncthreads();
    }

    float* X1 = soa + 0 * SOA_ARR + b * SOA_STRIDE;
    float* Y1 = soa + 1 * SOA_ARR + b * SOA_STRIDE;
    float* X2 = soa + 2 * SOA_ARR + b * SOA_STRIDE;
    float* Y2 = soa + 3 * SOA_ARR + b * SOA_STRIDE;
    float* Wd = soa + 4 * SOA_ARR + b * SOA_STRIDE;
    float* Hd = soa + 5 * SOA_ARR + b * SOA_STRIDE;
    for (int p = tid; p < NBOX; p += NT1) {
        unsigned long long kk = skey[p];
        int n = (int)(unsigned)(kk & 0xffffffffull);
        float det = __uint_as_float(~(unsigned)(kk >> 32));
        float4 bx = sbox[n];
        X1[p] = bx.x - 0.5f * bx.z;
        Y1[p] = bx.y - 0.5f * bx.w;
        X2[p] = bx.x + 0.5f * bx.z;
        Y2[p] = bx.y + 0.5f * bx.w;
        Wd[p] = bx.z;
        Hd[p] = bx.w;
        if (det > CONF_T) {
            float dn = 0.0f;
            if (p + 1 < NBOX) dn = __uint_as_float(~(unsigned)(skey[p + 1] >> 32));
            if (!(dn > CONF_T)) sM = p + 1;      // unique boundary thread
        }
    }
    __syncthreads();
    if (tid == 0) Marr[b] = sM;
}

// ---- K2: suppression bitmask, XCD-swizzled: batch = blockIdx % 8 ----
__global__ __launch_bounds__(256) void k_iou_mask(
    const float* __restrict__ soa, const int* __restrict__ Marr,
    unsigned long long* __restrict__ sup)
{
    const int blk  = blockIdx.x;
    const int b    = blk & 7;                       // XCD-local to k_nms_match's block b
    const int lane = threadIdx.x & 63;
    const int i    = (blk >> 3) * 4 + (threadIdx.x >> 6);
    const int M = Marr[b];
    if (i >= M) return;
    const float* X1 = soa + 0 * SOA_ARR + b * SOA_STRIDE;
    const float* Y1 = soa + 1 * SOA_ARR + b * SOA_STRIDE;
    const float* X2 = soa + 2 * SOA_ARR + b * SOA_STRIDE;
    const float* Y2 = soa + 3 * SOA_ARR + b * SOA_STRIDE;
    const float* Wd = soa + 4 * SOA_ARR + b * SOA_STRIDE;
    const float* Hd = soa + 5 * SOA_ARR + b * SOA_STRIDE;
    float ax1 = X1[i], ay1 = Y1[i], ax2 = X2[i], ay2 = Y2[i];
    float aw = Wd[i], ah = Hd[i], aarea = aw * ah;
    const int nch = (M + 63) >> 6;
    unsigned long long myw = 0;
    for (int w = 0; w < nch; ++w) {
        int j = (w << 6) + lane;
        bool pred = false;
        if (j > i && j < M) {
            float bw = Wd[j], bh = Hd[j];
            float uw = fmaxf(ax2, X2[j]) - fminf(ax1, X1[j]);
            float uh = fmaxf(ay2, Y2[j]) - fminf(ay1, Y1[j]);
            float cw = aw + bw - uw;
            float ch = ah + bh - uh;
            if (cw > 0.0f && ch > 0.0f) {
                float ca = cw * ch;
                float ua = aarea + bw * bh - ca;
                pred = ca > NMS_T * ua;          // iou > thresh
            }
        }
        unsigned long long m = __ballot(pred);
        if (w == lane) myw = m;
    }
    unsigned long long* row = sup + ((size_t)b * SUP_ROWS + i) * SUP_WORDS;
    if (lane < SUP_WORDS) row[lane] = (lane < nch) ? myw : 0ull;
}

// ---- K3: deep-prefetch greedy bit-sweep + GT match + final metrics ----
__global__ __launch_bounds__(256, 1) void k_nms_match(
    const float* __restrict__ soa, const float* __restrict__ tgt,
    const int* __restrict__ Marr, const unsigned long long* __restrict__ sup,
    int* __restrict__ counters, float* __restrict__ out)
{
    __shared__ unsigned long long kw[SUP_WORDS];
    __shared__ int sProp, sCorr, sNV;
    const int b = blockIdx.x, tid = threadIdx.x;
    const int wv = tid >> 6, lane = tid & 63;
    const int M = Marr[b];
    const int nw = (M + 63) >> 6;

    if (wv == 1 && lane == 0) sCorr = 0;

    if (wv == 0) {
        // GT count via ballot (first row with cx==0); uniform data -> usually 50
        float cxv = (lane < TMAX) ? tgt[b * 250 + lane * 5 + 1] : 0.0f;
        unsigned long long bm = __ballot(cxv != 0.0f);
        unsigned long long inv = (~bm) & ((1ull << TMAX) - 1);
        int nv = inv ? (__ffsll((long long)inv) - 1) : TMAX;
        if (lane == 0) sNV = nv;

        // greedy sweep: lane l owns word min(l,31); depth-32 double-buffered prefetch
        const unsigned long long* sp = sup + (size_t)b * SUP_ROWS * SUP_WORDS;
        const int mylw = (lane < SUP_WORDS) ? lane : (SUP_WORDS - 1);
        unsigned long long A[32], B[32];
        unsigned long long rm = 0, rmw = 0;
        #pragma unroll
        for (int r = 0; r < 32; ++r)
            A[r] = sp[(size_t)r * SUP_WORDS + mylw];

        for (int g0 = 0; g0 < M; g0 += 64) {
            const int w = g0 >> 6;
            #pragma unroll
            for (int r = 0; r < 32; ++r) {
                int row = g0 + 32 + r; row = (row < SUP_ROWS) ? row : (SUP_ROWS - 1);
                B[r] = sp[(size_t)row * SUP_WORDS + mylw];
            }
            #pragma unroll
            for (int r = 0; r < 32; ++r) {
                unsigned long long q = shflw(A[r], w);   // row's word w (off-chain)
                int i = g0 + r;
                bool kept = (i < M) && !((rmw >> (i & 63)) & 1);
                unsigned long long km = kept ? ~0ull : 0ull;
                rm  |= A[r] & km;
                rmw |= q    & km;
            }
            #pragma unroll
            for (int r = 0; r < 32; ++r) {
                int row = g0 + 64 + r; row = (row < SUP_ROWS) ? row : (SUP_ROWS - 1);
                A[r] = sp[(size_t)row * SUP_WORDS + mylw];
            }
            #pragma unroll
            for (int r = 0; r < 32; ++r) {
                unsigned long long q = shflw(B[r], w);
                int i = g0 + 32 + r;
                bool kept = (i < M) && !((rmw >> (i & 63)) & 1);
                unsigned long long km = kept ? ~0ull : 0ull;
                rm  |= B[r] & km;
                rmw |= q    & km;
            }
            int wn = w + 1; wn = (wn < SUP_WORDS) ? wn : (SUP_WORDS - 1);
            rmw = shflw(rm, wn);                         // refresh for next word
        }

        unsigned long long keepv = 0;
        if (lane < nw) {
            int rem = M - (lane << 6);
            unsigned long long vm = (rem >= 64) ? ~0ull : ((1ull << rem) - 1ull);
            keepv = (~rm) & vm;
        }
        if (lane < SUP_WORDS) kw[lane] = (lane < nw) ? keepv : 0ull;
        int pc = __popcll(keepv);
        for (int d = 32; d > 0; d >>= 1) pc += __shfl_down(pc, d, 64);
        if (lane == 0) sProp = pc;
    }
    __syncthreads();

    // GT matching: wave per GT row, lanes stripe boxes
    const float* X1 = soa + 0 * SOA_ARR + b * SOA_STRIDE;
    const float* Y1 = soa + 1 * SOA_ARR + b * SOA_STRIDE;
    const float* X2 = soa + 2 * SOA_ARR + b * SOA_STRIDE;
    const float* Y2 = soa + 3 * SOA_ARR + b * SOA_STRIDE;
    const float* Wd = soa + 4 * SOA_ARR + b * SOA_STRIDE;
    const float* Hd = soa + 5 * SOA_ARR + b * SOA_STRIDE;
    const int nv = sNV;
    for (int t = wv; t < nv; t += 4) {
        const float* g = tgt + b * 250 + t * 5;
        float gcx = g[1], gcy = g[2], gw = g[3], gh = g[4];
        float gx1 = gcx - 0.5f * gw, gx2 = gcx + 0.5f * gw;
        float gy1 = gcy - 0.5f * gh, gy2 = gcy + 0.5f * gh;
        float garea = gw * gh;
        float best = 0.0f;
        for (int j = lane; j < M; j += 64) {
            if (!((kw[j >> 6] >> (j & 63)) & 1)) continue;
            float bw = Wd[j], bh = Hd[j];
            float uw = fmaxf(gx2, X2[j]) - fminf(gx1, X1[j]);
            float uh = fmaxf(gy2, Y2[j]) - fminf(gy1, Y1[j]);
            float cw = gw + bw - uw;
            float ch = gh + bh - uh;
            float ca = (cw > 0.0f && ch > 0.0f) ? cw * ch : 0.0f;
            float ua = garea + bw * bh - ca;
            best = fmaxf(best, ca / ua);
        }
        for (int d = 32; d > 0; d >>= 1) best = fmaxf(best, __shfl_down(best, d, 64));
        if (lane == 0 && best > IOU_T) atomicAdd(&sCorr, 1);
    }
    __syncthreads();

    if (tid == 0) {
        atomicAdd(counters + 0, sProp);
        atomicAdd(counters + 1, sCorr);
        atomicAdd(counters + 2, sNV);
        __threadfence();
        int done = atomicAdd(counters + 3, 1);
        if (done == 7) {                      // last block computes final metrics
            float prop  = (float)atomicAdd(counters + 0, 0);
            float corr  = (float)atomicAdd(counters + 1, 0);
            float total = (float)atomicAdd(counters + 2, 0);
            float prec = corr / (prop + 1e-6f);
            float rec  = corr / (total + 1e-6f);
            float fs   = 2.0f * prec * rec / (prec + rec + 1e-6f);
            out[0] = total;
            out[1] = prop;
            out[2] = corr;
            out[3] = prec;
            out[4] = rec;
            out[5] = fs;
        }
    }
}

extern "C" void kernel_launch(void* const* d_in, const int* in_sizes, int n_in,
                              void* d_out, int out_size, void* d_ws, size_t ws_size,
                              hipStream_t stream) {
    const float* net = (const float*)d_in[0];   // [8,125,19,19] f32
    const float* tgt = (const float*)d_in[1];   // [8,250] f32
    char* ws = (char*)d_ws;
    int* counters = (int*)(ws + WS_COUNT);
    int* Marr     = (int*)(ws + WS_M);
    float* soa    = (float*)(ws + WS_SOA);
    unsigned long long* sup = (unsigned long long*)(ws + WS_SUP);

    hipMemsetAsync(counters, 0, 16, stream);
    k_decode_sort<<<8, NT1, 0, stream>>>(net, soa, Marr);
    int nchunk = (NBOX + 3) / 4;
    k_iou_mask<<<nchunk * 8, 256, 0, stream>>>(soa, Marr, sup);
    k_nms_match<<<8, 256, 0, stream>>>(soa, tgt, Marr, sup, counters, (float*)d_out);
}